// Round 10
// baseline (143.245 us; speedup 1.0000x reference)
//
#include <hip/hip_runtime.h>
#include <hip/hip_cooperative_groups.h>
#include <math.h>

namespace cg = cooperative_groups;

#define NMAX 3008
#define CAPC 128      // member compaction capacity
#define NCLS 80
#define IC   12       // i-chunks (12*256 >= 3000)
#define JC   16       // j-chunks
#define JCH  192      // >= ceil(3000/16)
#define GRID (IC*JC)  // 192 blocks

// ---- workspace layout (bytes) ----
#define WS_FSCORE 0                         // float[NMAX] frozen score by box
#define WS_PART   (4*NMAX)                  // u32[JC][NMAX]: gt | eqlt<<10 | eq<<20

// full-wave (64) max via DPP (VALU latency); uniform result in all lanes.
__device__ __forceinline__ float wave_max64(float x) {
    int v;
    v = __float_as_int(x);
    x = fmaxf(x, __int_as_float(__builtin_amdgcn_update_dpp(v, v, 0x111, 0xf, 0xf, false)));
    v = __float_as_int(x);
    x = fmaxf(x, __int_as_float(__builtin_amdgcn_update_dpp(v, v, 0x112, 0xf, 0xf, false)));
    v = __float_as_int(x);
    x = fmaxf(x, __int_as_float(__builtin_amdgcn_update_dpp(v, v, 0x114, 0xf, 0xf, false)));
    v = __float_as_int(x);
    x = fmaxf(x, __int_as_float(__builtin_amdgcn_update_dpp(v, v, 0x118, 0xf, 0xf, false)));
    v = __float_as_int(x);
    x = fmaxf(x, __int_as_float(__builtin_amdgcn_update_dpp(v, v, 0x142, 0xa, 0xf, false)));
    v = __float_as_int(x);
    x = fmaxf(x, __int_as_float(__builtin_amdgcn_update_dpp(v, v, 0x143, 0xc, 0xf, false)));
    return __int_as_float(__builtin_amdgcn_readlane(__float_as_int(x), 63));
}

// ---------------- single fused cooperative kernel ----------------
__global__ void __launch_bounds__(256)
fused_nms_kernel(const float* __restrict__ boxes, const float* __restrict__ scores,
                 const int* __restrict__ idxs, char* __restrict__ ws,
                 float* __restrict__ out, int n) {
#pragma clang fp contract(off)
    cg::grid_group grid = cg::this_grid();
    const int tid = threadIdx.x, wid = tid >> 6, lane = tid & 63;
    float* fscore = (float*)(ws + WS_FSCORE);
    unsigned* PART = (unsigned*)(ws + WS_PART);

    // phase A LDS
    __shared__ int idxS[NMAX];                 // 12 KB
    __shared__ unsigned long long maskS[NMAX / 64];
    __shared__ float mx0[CAPC], mx1[CAPC], mx2[CAPC], mx3[CAPC], msc[CAPC];
    __shared__ unsigned short mgid[CAPC];
    __shared__ float D[64 * 64];               // 16 KB
    __shared__ float redS[256];
    // phase B/C LDS
    __shared__ float sv[JCH];
    __shared__ unsigned short ordL[NMAX];
    __shared__ float          svL[NMAX];
    __shared__ unsigned short slotL[NMAX];
    __shared__ unsigned short batL[NMAX];
    __shared__ unsigned char  tieL[NMAX];
    __shared__ int rstopS;

    // ================= phase A: per-class soft-NMS (blocks 0..79) =================
    const int c = blockIdx.x;
    if (c < NCLS) {
        // stage idxs + global coord max (order-independent -> bit-exact)
        float m = -1e30f;
        for (int k = tid; k < n; k += 256) {
            idxS[k] = idxs[k];
            float4 bb = ((const float4*)boxes)[k];
            m = fmaxf(m, fmaxf(fmaxf(bb.x, bb.y), fmaxf(bb.z, bb.w)));
        }
        redS[tid] = m;
        __syncthreads();
        for (int s = 128; s > 0; s >>= 1) {
            if (tid < s) redS[tid] = fmaxf(redS[tid], redS[tid + s]);
            __syncthreads();
        }
        const float maxcp1 = redS[0] + 1.0f;
        const float off = (float)c * maxcp1;

        // membership masks (4 waves)
        const int nch = (n + 63) / 64;
        for (int t = wid; t < nch; t += 4) {
            int k = t * 64 + lane;
            bool p = (k < n) && (idxS[k] == c);
            unsigned long long mk = __ballot(p);
            if (lane == 0) maskS[t] = mk;
        }
        __syncthreads();

        // parallel member loads (4 waves share the prefix walk)
        int run = 0;
        for (int t = 0; t < nch; t++) {
            unsigned long long mk = maskS[t];
            if ((t & 3) == wid) {
                if ((mk >> lane) & 1ull) {
                    int pos = run + __popcll(mk & ((1ull << lane) - 1ull));
                    if (pos < CAPC) {
                        int k = t * 64 + lane;
                        float4 bb = ((const float4*)boxes)[k];
                        mx0[pos] = bb.x + off; mx1[pos] = bb.y + off;
                        mx2[pos] = bb.z + off; mx3[pos] = bb.w + off;
                        msc[pos] = scores[k];
                        mgid[pos] = (unsigned short)k;
                    }
                }
            }
            run += __popcll(mk);
        }
        const int cnt = run < CAPC ? run : CAPC;
        __syncthreads();

        if (cnt <= 64) {
            // decay matrix rows split across 4 waves (exp latency parallel)
            const bool v0 = lane < cnt;
            float c0 = 0, c1 = 0, c2 = 0, c3 = 0;
            if (v0) { c0 = mx0[lane]; c1 = mx1[lane]; c2 = mx2[lane]; c3 = mx3[lane]; }
            const float ab = (c2 - c0) * (c3 - c1);
            for (int i = wid; i < cnt; i += 4) {
                float w0 = mx0[i], w1 = mx1[i], w2 = mx2[i], w3 = mx3[i];
                float aw = (w2 - w0) * (w3 - w1);
                float x1 = fmaxf(w0, c0), y1 = fmaxf(w1, c1);
                float x2 = fminf(w2, c2), y2 = fminf(w3, c3);
                float iw = fmaxf(x2 - x1, 0.f), ih = fmaxf(y2 - y1, 0.f);
                float inter = iw * ih;
                float d = 1.0f;                 // exp(-0.0) == 1.0f exactly
                if (inter != 0.f) {
                    float iou = inter / ((aw + ab) - inter);
                    float arg = -(iou * iou) / 0.5f;
                    d = (float)exp((double)arg);
                }
                D[i * 64 + lane] = d;
            }
            __syncthreads();

            if (wid == 0) {                     // serial selection (validated bit-exact)
                float sc = v0 ? msc[lane] : -1.f;
                int g = v0 ? mgid[lane] : 0;
                float frz = 0.f;
                for (int s = 0; s < cnt; s++) {
                    float M = wave_max64(sc);
                    int wm = __ffsll(__ballot(sc == M)) - 1;
                    float d = D[wm * 64 + lane];
                    if (lane == wm) { frz = M; sc = -1.f; }
                    else if (sc >= 0.f) sc = sc * d;
                }
                if (v0) fscore[g] = frz;
            }
        } else if (wid == 0) {
            // fallback (cnt > 64): validated 2-slot in-loop path
            float sc0 = -1.f, sc1 = -1.f;
            float a0 = 0, a1 = 0, a2 = 0, a3 = 0, b0 = 0, b1 = 0, b2 = 0, b3 = 0;
            int g0 = 0, g1 = 0;
            if (lane < cnt) {
                sc0 = msc[lane];
                a0 = mx0[lane]; a1 = mx1[lane]; a2 = mx2[lane]; a3 = mx3[lane];
                g0 = mgid[lane];
            }
            if (64 + lane < cnt) {
                sc1 = msc[64 + lane];
                b0 = mx0[64 + lane]; b1 = mx1[64 + lane]; b2 = mx2[64 + lane]; b3 = mx3[64 + lane];
                g1 = mgid[64 + lane];
            }
            for (int s = 0; s < cnt; s++) {
                float M = fmaxf(sc0, sc1);
                for (int o = 32; o >= 1; o >>= 1) M = fmaxf(M, __shfl_xor(M, o, 64));
                unsigned long long balA = __ballot(sc0 == M);
                int wm;
                if (balA) wm = __ffsll(balA) - 1;
                else      wm = 64 + __ffsll(__ballot(sc1 == M)) - 1;
                float w0 = mx0[wm], w1 = mx1[wm], w2 = mx2[wm], w3 = mx3[wm];
                if (wm == lane)           { fscore[g0] = M; sc0 = -1.f; }
                else if (wm == 64 + lane) { fscore[g1] = M; sc1 = -1.f; }
                float area_w = (w2 - w0) * (w3 - w1);
                if (sc0 >= 0.f) {
                    float x1 = fmaxf(w0, a0), y1 = fmaxf(w1, a1);
                    float x2 = fminf(w2, a2), y2 = fminf(w3, a3);
                    float iw = fmaxf(x2 - x1, 0.f), ih = fmaxf(y2 - y1, 0.f);
                    float inter = iw * ih;
                    float area_b = (a2 - a0) * (a3 - a1);
                    float iou = inter / ((area_w + area_b) - inter);
                    float arg = -(iou * iou) / 0.5f;
                    sc0 = sc0 * (float)exp((double)arg);
                }
                if (sc1 >= 0.f) {
                    float x1 = fmaxf(w0, b0), y1 = fmaxf(w1, b1);
                    float x2 = fminf(w2, b2), y2 = fminf(w3, b3);
                    float iw = fmaxf(x2 - x1, 0.f), ih = fmaxf(y2 - y1, 0.f);
                    float inter = iw * ih;
                    float area_b = (b2 - b0) * (b3 - b1);
                    float iou = inter / ((area_w + area_b) - inter);
                    float arg = -(iou * iou) / 0.5f;
                    sc1 = sc1 * (float)exp((double)arg);
                }
            }
        }
    }

    grid.sync();   // fscore complete & visible device-wide

    // ================= phase B: rank partials (all 192 blocks) =================
    {
        const int bx = blockIdx.x % IC;
        const int by = blockIdx.x / IC;
        const int chunk = (n + JC - 1) / JC;   // 188: per-chunk counts fit 10 bits
        const int j0 = by * chunk;
        const int jn = min(n - j0, chunk);
        for (int j = tid; j < jn; j += 256) sv[j] = fscore[j0 + j];
        __syncthreads();

        int i = bx * 256 + tid;
        if (i < n) {
            float s = fscore[i];
            int gt = 0, eq = 0, eqlt = 0;
            for (int jj = 0; jj < jn; jj++) {
                float x = sv[jj];
                gt   += (x > s) ? 1 : 0;
                eq   += (x == s) ? 1 : 0;
                eqlt += (x == s && (j0 + jj) < i) ? 1 : 0;
            }
            PART[by * NMAX + i] = (unsigned)gt | ((unsigned)eqlt << 10) | ((unsigned)eq << 20);
        }
    }

    grid.sync();   // PART complete & visible device-wide

    // ================= phase C: finalize (block 0 only) =================
    if (blockIdx.x != 0) return;
    if (tid == 0) rstopS = 0;
    __syncthreads();

    for (int b = tid; b < n; b += 256) {
        unsigned gt = 0, eqlt = 0, eq = 0;
#pragma unroll
        for (int jc = 0; jc < JC; jc++) {
            unsigned p = PART[jc * NMAX + b];
            gt   += p & 1023u;
            eqlt += (p >> 10) & 1023u;
            eq   += (p >> 20) & 1023u;
        }
        int r = (int)(gt + eqlt);
        ordL[r] = (unsigned short)b;
        svL[r] = fscore[b];
        slotL[b] = (unsigned short)b;
        batL[b]  = (unsigned short)b;
        // unsafe group: a member's id < group START (gt); members with id >= gt
        // provably still sit at slot == id when the group is emitted.
        if (eq >= 2 && (unsigned)b < gt) atomicMax(&rstopS, (int)(gt + eq));
    }
    __syncthreads();

    for (int r = tid; r < n; r += 256)
        tieL[r] = (r + 1 < n) && (svL[r] == svL[r + 1]);
    __syncthreads();

    if (rstopS > 0 && tid == 0) {
        const int rstop = rstopS;
        int r = 0;
        while (r < rstop) {
            if (!tieL[r]) {
                int w = ordL[r];
                int j = slotL[w];
                int d = batL[r];
                batL[j] = (unsigned short)d;
                slotL[d] = (unsigned short)j;
                r++;
            } else {
                int g = 1;
                while (tieL[r + g - 1]) g++;
                for (int t = 0; t < g; t++) {
                    int bi = r + t;
                    int bs = slotL[ordL[bi]];
                    for (int q = r + t + 1; q < r + g; q++) {
                        int s2 = slotL[ordL[q]];
                        if (s2 < bs) { bs = s2; bi = q; }
                    }
                    unsigned short w = ordL[bi];
                    ordL[bi] = ordL[r + t];
                    ordL[r + t] = w;
                    int d = batL[r + t];
                    batL[bs] = (unsigned short)d;
                    slotL[d] = (unsigned short)bs;
                }
                r += g;
            }
        }
    }
    __syncthreads();

    for (int r = tid; r < n; r += 256) {
        float s = svL[r];
        out[r] = s;
        out[n + r] = (float)ordL[r];
        out[2 * n + r] = (s > 0.05f) ? 1.f : 0.f;
    }
}

extern "C" void kernel_launch(void* const* d_in, const int* in_sizes, int n_in,
                              void* d_out, int out_size, void* d_ws, size_t ws_size,
                              hipStream_t stream) {
    const float* boxes  = (const float*)d_in[0];  // [N,4] f32
    const float* scores = (const float*)d_in[1];  // [N]   f32
    const int*   idxs   = (const int*)d_in[2];    // [N]   i32
    float* out = (float*)d_out;                   // scores | order | keep (f32)
    char* ws = (char*)d_ws;
    int n = in_sizes[1];

    void* args[] = { (void*)&boxes, (void*)&scores, (void*)&idxs,
                     (void*)&ws, (void*)&out, (void*)&n };
    hipLaunchCooperativeKernel((const void*)fused_nms_kernel,
                               dim3(GRID), dim3(256), args, 0, stream);
}

// Round 11
// 95.354 us; speedup vs baseline: 1.5022x; 1.5022x over previous
//
#include <hip/hip_runtime.h>
#include <math.h>

#define NMAX 3008
#define NCH  47       // ceil(3008/64) chunks
#define CAPC 128      // member compaction capacity
#define NCLS 80
#define TB   512      // threads per block (8 waves)
#define IC   6        // i-chunks for rank (6*512 >= 3000)
#define JC   16       // j-chunks
#define JCH  192
#define RB   (IC*JC)  // 96 rank blocks

// ---- workspace layout (bytes) ----
#define WS_DONE   0                         // u32 done counter
#define WS_FSCORE 16                        // float[NMAX] frozen score by box
#define WS_RANKC  (WS_FSCORE + 4*NMAX)      // u64[NMAX]: gt | eqlt<<16 | eq<<32

// full-wave (64) max via DPP (VALU latency); uniform result in all lanes.
__device__ __forceinline__ float wave_max64(float x) {
    int v;
    v = __float_as_int(x);
    x = fmaxf(x, __int_as_float(__builtin_amdgcn_update_dpp(v, v, 0x111, 0xf, 0xf, false)));
    v = __float_as_int(x);
    x = fmaxf(x, __int_as_float(__builtin_amdgcn_update_dpp(v, v, 0x112, 0xf, 0xf, false)));
    v = __float_as_int(x);
    x = fmaxf(x, __int_as_float(__builtin_amdgcn_update_dpp(v, v, 0x114, 0xf, 0xf, false)));
    v = __float_as_int(x);
    x = fmaxf(x, __int_as_float(__builtin_amdgcn_update_dpp(v, v, 0x118, 0xf, 0xf, false)));
    v = __float_as_int(x);
    x = fmaxf(x, __int_as_float(__builtin_amdgcn_update_dpp(v, v, 0x142, 0xa, 0xf, false)));
    v = __float_as_int(x);
    x = fmaxf(x, __int_as_float(__builtin_amdgcn_update_dpp(v, v, 0x143, 0xc, 0xf, false)));
    return __int_as_float(__builtin_amdgcn_readlane(__float_as_int(x), 63));
}

// ---------------- kernel 1: per-class soft-NMS (8-wave prep, wave-0 select) ----------------
__global__ void __launch_bounds__(TB)
nms_class_kernel(const float* __restrict__ boxes, const float* __restrict__ scores,
                 const int* __restrict__ idxs, char* __restrict__ ws, int n) {
#pragma clang fp contract(off)
    const int c = blockIdx.x;
    const int tid = threadIdx.x, wid = tid >> 6, lane = tid & 63;
    float* fscore = (float*)(ws + WS_FSCORE);
    unsigned long long* RANKC = (unsigned long long*)(ws + WS_RANKC);

    __shared__ unsigned long long maskS[NCH];
    __shared__ float mx0[CAPC], mx1[CAPC], mx2[CAPC], mx3[CAPC], msc[CAPC];
    __shared__ unsigned short mgid[CAPC];
    __shared__ float D[64 * 64];               // 16 KB
    __shared__ float redS[TB / 64];

    // zero shared counters for the next dispatch (stream-ordered)
    for (int i = c * TB + tid; i < NMAX; i += NCLS * TB) RANKC[i] = 0ull;
    if (c == 0 && tid == 0) *(unsigned*)(ws + WS_DONE) = 0u;

    // phase 1: fused idx load + membership ballot + coord max. Wave w owns
    // chunks t with t%8 == w (same assignment reused in the member-load pass).
    float m = -1e30f;
    for (int t = wid; t < NCH; t += 8) {
        int k = t * 64 + lane;
        bool p = false;
        if (k < n) {
            p = (idxs[k] == c);
            float4 bb = ((const float4*)boxes)[k];
            m = fmaxf(m, fmaxf(fmaxf(bb.x, bb.y), fmaxf(bb.z, bb.w)));
        }
        unsigned long long mk = __ballot(p);
        if (lane == 0) maskS[t] = mk;
    }
    m = wave_max64(m);
    if (lane == 0) redS[wid] = m;
    __syncthreads();
    float mm = redS[0];
#pragma unroll
    for (int w = 1; w < TB / 64; w++) mm = fmaxf(mm, redS[w]);   // order-indep max -> exact
    const float maxcp1 = mm + 1.0f;
    const float off = (float)c * maxcp1;

    // phase 2: member loads; all waves walk the uniform prefix, each loads its chunks
    int run = 0;
    for (int t = 0; t < NCH; t++) {
        unsigned long long mk = maskS[t];
        if ((t & 7) == wid) {
            if ((mk >> lane) & 1ull) {
                int pos = run + __popcll(mk & ((1ull << lane) - 1ull));
                if (pos < CAPC) {
                    int k = t * 64 + lane;
                    float4 bb = ((const float4*)boxes)[k];      // L1/L2-warm
                    mx0[pos] = bb.x + off; mx1[pos] = bb.y + off;
                    mx2[pos] = bb.z + off; mx3[pos] = bb.w + off;
                    msc[pos] = scores[k];
                    mgid[pos] = (unsigned short)k;
                }
            }
        }
        run += __popcll(mk);
    }
    const int cnt = run < CAPC ? run : CAPC;
    __syncthreads();

    if (cnt <= 64) {
        // phase 3 (8 waves): decay rows split across waves; exp(-0.0)==1.0f skip
        const bool v0 = lane < cnt;
        float c0 = 0, c1 = 0, c2 = 0, c3 = 0;
        if (v0) { c0 = mx0[lane]; c1 = mx1[lane]; c2 = mx2[lane]; c3 = mx3[lane]; }
        const float ab = (c2 - c0) * (c3 - c1);
        for (int i = wid; i < cnt; i += 8) {
            float w0 = mx0[i], w1 = mx1[i], w2 = mx2[i], w3 = mx3[i];
            float aw = (w2 - w0) * (w3 - w1);
            float x1 = fmaxf(w0, c0), y1 = fmaxf(w1, c1);
            float x2 = fminf(w2, c2), y2 = fminf(w3, c3);
            float iw = fmaxf(x2 - x1, 0.f), ih = fmaxf(y2 - y1, 0.f);
            float inter = iw * ih;
            float d = 1.0f;
            if (inter != 0.f) {
                float iou = inter / ((aw + ab) - inter);
                float arg = -(iou * iou) / 0.5f;
                d = (float)exp((double)arg);
            }
            D[i * 64 + lane] = d;
        }
        __syncthreads();

        // phase 4 (wave 0): serial selection — validated bit-exact (r2-r9)
        if (wid == 0) {
            float sc = v0 ? msc[lane] : -1.f;
            int g = v0 ? mgid[lane] : 0;
            float frz = 0.f;
            for (int s = 0; s < cnt; s++) {
                float M = wave_max64(sc);
                int wm = __ffsll(__ballot(sc == M)) - 1;
                float d = D[wm * 64 + lane];
                if (lane == wm) { frz = M; sc = -1.f; }
                else if (sc >= 0.f) sc = sc * d;
            }
            if (v0) fscore[g] = frz;
        }
    } else if (wid == 0) {
        // fallback (cnt > 64): validated 2-slot in-loop path
        float sc0 = -1.f, sc1 = -1.f;
        float a0 = 0, a1 = 0, a2 = 0, a3 = 0, b0 = 0, b1 = 0, b2 = 0, b3 = 0;
        int g0 = 0, g1 = 0;
        if (lane < cnt) {
            sc0 = msc[lane];
            a0 = mx0[lane]; a1 = mx1[lane]; a2 = mx2[lane]; a3 = mx3[lane];
            g0 = mgid[lane];
        }
        if (64 + lane < cnt) {
            sc1 = msc[64 + lane];
            b0 = mx0[64 + lane]; b1 = mx1[64 + lane]; b2 = mx2[64 + lane]; b3 = mx3[64 + lane];
            g1 = mgid[64 + lane];
        }
        for (int s = 0; s < cnt; s++) {
            float M = fmaxf(sc0, sc1);
            for (int o = 32; o >= 1; o >>= 1) M = fmaxf(M, __shfl_xor(M, o, 64));
            unsigned long long balA = __ballot(sc0 == M);
            int wm;
            if (balA) wm = __ffsll(balA) - 1;
            else      wm = 64 + __ffsll(__ballot(sc1 == M)) - 1;
            float w0 = mx0[wm], w1 = mx1[wm], w2 = mx2[wm], w3 = mx3[wm];
            if (wm == lane)           { fscore[g0] = M; sc0 = -1.f; }
            else if (wm == 64 + lane) { fscore[g1] = M; sc1 = -1.f; }
            float area_w = (w2 - w0) * (w3 - w1);
            if (sc0 >= 0.f) {
                float x1 = fmaxf(w0, a0), y1 = fmaxf(w1, a1);
                float x2 = fminf(w2, a2), y2 = fminf(w3, a3);
                float iw = fmaxf(x2 - x1, 0.f), ih = fmaxf(y2 - y1, 0.f);
                float inter = iw * ih;
                float area_b = (a2 - a0) * (a3 - a1);
                float iou = inter / ((area_w + area_b) - inter);
                float arg = -(iou * iou) / 0.5f;
                sc0 = sc0 * (float)exp((double)arg);
            }
            if (sc1 >= 0.f) {
                float x1 = fmaxf(w0, b0), y1 = fmaxf(w1, b1);
                float x2 = fminf(w2, b2), y2 = fminf(w3, b3);
                float iw = fmaxf(x2 - x1, 0.f), ih = fmaxf(y2 - y1, 0.f);
                float inter = iw * ih;
                float area_b = (b2 - b0) * (b3 - b1);
                float iou = inter / ((area_w + area_b) - inter);
                float arg = -(iou * iou) / 0.5f;
                sc1 = sc1 * (float)exp((double)arg);
            }
        }
    }
}

// ---------------- kernel 2: fused rank + finalize (last-block pattern) ----------------
__global__ void __launch_bounds__(TB)
rank_finalize_kernel(char* __restrict__ ws, float* __restrict__ out, int n) {
    const int tid = threadIdx.x;
    float* fscore = (float*)(ws + WS_FSCORE);
    unsigned long long* RANKC = (unsigned long long*)(ws + WS_RANKC);
    unsigned* done = (unsigned*)(ws + WS_DONE);

    __shared__ float sv[JCH];

    // ---- rank phase: block = (i-chunk bx, j-chunk by) ----
    const int bx = blockIdx.x % IC;
    const int by = blockIdx.x / IC;
    const int chunk = (n + JC - 1) / JC;
    const int j0 = by * chunk;
    const int jn = min(n - j0, chunk);
    for (int j = tid; j < jn; j += TB) sv[j] = fscore[j0 + j];
    __syncthreads();

    int i = bx * TB + tid;
    if (i < n) {
        float s = fscore[i];
        int gt = 0, eq = 0, eqlt = 0;
        for (int jj = 0; jj < jn; jj++) {
            float x = sv[jj];
            gt   += (x > s) ? 1 : 0;
            eq   += (x == s) ? 1 : 0;
            eqlt += (x == s && (j0 + jj) < i) ? 1 : 0;
        }
        unsigned long long packed = (unsigned long long)(unsigned)gt
                                  | ((unsigned long long)(unsigned)eqlt << 16)
                                  | ((unsigned long long)(unsigned)eq << 32);
        atomicAdd(&RANKC[i], packed);
    }
    __syncthreads();
    __threadfence();

    __shared__ int lastS;
    if (tid == 0) lastS = (atomicAdd(done, 1u) == RB - 1);
    __syncthreads();
    if (!lastS) return;

    // ---- finalize phase (last-done block only) ----
    __shared__ unsigned short ordL[NMAX];
    __shared__ float          svL[NMAX];
    __shared__ unsigned short slotL[NMAX];
    __shared__ unsigned short batL[NMAX];
    __shared__ unsigned char  tieL[NMAX];
    __shared__ int rstopS;
    if (tid == 0) rstopS = 0;
    __syncthreads();

    for (int b = tid; b < n; b += TB) {
        unsigned long long p = atomicAdd(&RANKC[b], 0ull);   // device-coherent read
        unsigned gt   = (unsigned)(p & 0xffffu);
        unsigned eqlt = (unsigned)((p >> 16) & 0xffffu);
        unsigned eq   = (unsigned)((p >> 32) & 0xffffu);
        int r = (int)(gt + eqlt);
        ordL[r] = (unsigned short)b;
        svL[r] = fscore[b];
        slotL[b] = (unsigned short)b;
        batL[b]  = (unsigned short)b;
        // unsafe group: a member's id < group START (gt); members with id >= gt
        // provably still sit at slot == id when the group is emitted.
        if (eq >= 2 && (unsigned)b < gt) atomicMax(&rstopS, (int)(gt + eq));
    }
    __syncthreads();

    for (int r = tid; r < n; r += TB)
        tieL[r] = (r + 1 < n) && (svL[r] == svL[r + 1]);
    __syncthreads();

    if (rstopS > 0 && tid == 0) {
        const int rstop = rstopS;
        int r = 0;
        while (r < rstop) {
            if (!tieL[r]) {
                int w = ordL[r];
                int j = slotL[w];
                int d = batL[r];
                batL[j] = (unsigned short)d;
                slotL[d] = (unsigned short)j;
                r++;
            } else {
                int g = 1;
                while (tieL[r + g - 1]) g++;
                for (int t = 0; t < g; t++) {
                    int bi = r + t;
                    int bs = slotL[ordL[bi]];
                    for (int q = r + t + 1; q < r + g; q++) {
                        int s2 = slotL[ordL[q]];
                        if (s2 < bs) { bs = s2; bi = q; }
                    }
                    unsigned short w = ordL[bi];
                    ordL[bi] = ordL[r + t];
                    ordL[r + t] = w;
                    int d = batL[r + t];
                    batL[bs] = (unsigned short)d;
                    slotL[d] = (unsigned short)bs;
                }
                r += g;
            }
        }
    }
    __syncthreads();

    for (int r = tid; r < n; r += TB) {
        float s = svL[r];
        out[r] = s;
        out[n + r] = (float)ordL[r];
        out[2 * n + r] = (s > 0.05f) ? 1.f : 0.f;
    }
}

extern "C" void kernel_launch(void* const* d_in, const int* in_sizes, int n_in,
                              void* d_out, int out_size, void* d_ws, size_t ws_size,
                              hipStream_t stream) {
    const float* boxes  = (const float*)d_in[0];  // [N,4] f32
    const float* scores = (const float*)d_in[1];  // [N]   f32
    const int*   idxs   = (const int*)d_in[2];    // [N]   i32
    float* out = (float*)d_out;                   // scores | order | keep (f32)
    char* ws = (char*)d_ws;
    const int n = in_sizes[1];

    nms_class_kernel<<<NCLS, TB, 0, stream>>>(boxes, scores, idxs, ws, n);
    rank_finalize_kernel<<<RB, TB, 0, stream>>>(ws, out, n);
}